// Round 1
// 190.719 us; speedup vs baseline: 1.0027x; 1.0027x over previous
//
#include <hip/hip_runtime.h>
#include <math.h>

// R16: counters showed outcomp WRITE_SIZE 40 MB vs 1.18 MB ideal (34x write
// amplification from o-on-lane-fast-axis scatter stores; out is [B][C][N]
// linear in token n!) and qkv latency-bound (141 GB/s, occ 5.9%, strided rgb
// gather, 144 blocks on 256 CUs). Fixes:
//  (a) xprep_kernel: LDS-tiled coalesced transpose of rgb + depth bilinear,
//      emitting token-major Xt[4][2304][64] fp32. Xt aliases the AOr/AOd
//      region (dead until attn, kernels stream-serialized) — no extra ws.
//  (b) qkv reads Xt contiguously (float4), tile 32 tokens, grid(72,4).
//  (c) outcomp restages GELU tile in LDS (stride-40 rows, 8-lane groups hit
//      all 8 4-bank groups) then writes out[(b*C+o)*2304+n] as full lines.
// attn (~53us, MfmaUtil 11.5%) untouched this round — next target.
#define BATCH 2
#define C 64
#define HH 48
#define WW 48
#define NTOK 2304
#define HEADS 8
#define KVSTRIDE 12

typedef unsigned short bf16_t;
typedef __attribute__((ext_vector_type(8))) short bf16x8;
typedef __attribute__((ext_vector_type(4))) float f32x4;

__device__ __forceinline__ bf16_t f2bf(float f) {
    unsigned int u = __float_as_uint(f);
    u = (u + 0x7fffu + ((u >> 16) & 1u)) >> 16;   // RNE
    return (bf16_t)u;
}
__device__ __forceinline__ unsigned pack2(float a, float b) {
    return (unsigned)f2bf(a) | ((unsigned)f2bf(b) << 16);
}
__device__ __forceinline__ float4 ld_bf4(const bf16_t* p) {
    uint2 v = *(const uint2*)p;
    float4 r;
    r.x = __uint_as_float(v.x << 16); r.y = __uint_as_float(v.x & 0xffff0000u);
    r.z = __uint_as_float(v.y << 16); r.w = __uint_as_float(v.y & 0xffff0000u);
    return r;
}

// Stage one token-row of X (fallback path only). strm 0: rgb transpose
// gather. strm 1: conv1x1+ReLU+bilinear x2 (half-pixel; clamp == jax edge
// renorm for 24->48).
__device__ __forceinline__ void stage_x_row(
    float* xrow, const float* rgb, const float* dep,
    const float* w_exp, const float* b_exp,
    int b, int n, int strm, int c0, int cstep)
{
    int wi = n / HH, hi = n % HH;
    if (strm == 0) {
        const float* base = rgb + (size_t)b * C * NTOK + (size_t)hi * WW + wi;
        for (int c = c0; c < 64; c += cstep)
            xrow[c] = base[(size_t)c * NTOK];
    } else {
        float cy = 0.5f * hi - 0.25f, cx = 0.5f * wi - 0.25f;
        float fy0 = floorf(cy), fx0 = floorf(cx);
        float fy = cy - fy0, fx = cx - fx0;
        int y0 = max((int)fy0, 0), x0 = max((int)fx0, 0);
        int y1 = min((int)fy0 + 1, 23), x1 = min((int)fx0 + 1, 23);
        const float* dp = dep + b * 576;
        float d00 = dp[y0*24 + x0], d01 = dp[y0*24 + x1];
        float d10 = dp[y1*24 + x0], d11 = dp[y1*24 + x1];
        for (int c = c0; c < 64; c += cstep) {
            float w = w_exp[c], bb = b_exp[c];
            float r00 = fmaxf(w*d00 + bb, 0.f), r01 = fmaxf(w*d01 + bb, 0.f);
            float r10 = fmaxf(w*d10 + bb, 0.f), r11 = fmaxf(w*d11 + bb, 0.f);
            xrow[c] = (1.f-fy)*((1.f-fx)*r00 + fx*r01) + fy*((1.f-fx)*r10 + fx*r11);
        }
    }
}

// ===========================================================================
// MAIN PATH (ws >= 5,931,264 B)
// ===========================================================================

// W1 = Wc[:, :64] @ Wrp ; W2 = Wc[:, 64:] @ Wdp ; beff = Wc@[br;bd] + bc.
__global__ __launch_bounds__(256) void wprep_kernel(
    const float* __restrict__ w_rp, const float* __restrict__ w_dp,
    const float* __restrict__ w_comp,
    const float* __restrict__ b_rp, const float* __restrict__ b_dp,
    const float* __restrict__ b_comp,
    float* __restrict__ W1, float* __restrict__ W2, float* __restrict__ beff)
{
    int bx = blockIdx.x, m = blockIdx.y;
    const float* Wp = m ? w_dp : w_rp;
    float* Wo = m ? W2 : W1;
    __shared__ float Wps[64][68];
    int tid = threadIdx.x;
    int sr = tid >> 4, sc4 = (tid & 15) * 4;
    #pragma unroll
    for (int rr = 0; rr < 4; ++rr) {
        int r = rr*16 + sr;
        *(float4*)&Wps[r][sc4] = *(const float4*)&Wp[r*64 + sc4];
    }
    __syncthreads();
    int r = tid >> 4;
    int o = bx*16 + r;
    int c4 = (tid & 15) * 4;
    float a0 = 0, a1 = 0, a2 = 0, a3 = 0;
    for (int j = 0; j < 64; ++j) {
        float wc = w_comp[o*128 + m*64 + j];
        float4 wp = *(const float4*)&Wps[j][c4];
        a0 += wc*wp.x; a1 += wc*wp.y; a2 += wc*wp.z; a3 += wc*wp.w;
    }
    Wo[o*64 + c4]     = a0;
    Wo[o*64 + c4 + 1] = a1;
    Wo[o*64 + c4 + 2] = a2;
    Wo[o*64 + c4 + 3] = a3;
    if (bx == 0 && m == 0 && tid < 64) {
        float s = b_comp[tid];
        for (int j = 0; j < 64; ++j)
            s += w_comp[tid*128 + j] * b_rp[j] + w_comp[tid*128 + 64 + j] * b_dp[j];
        beff[tid] = s;
    }
}

// Coalesced X preparation. grid(36, 4) = (memidx-tile, b*2+strm).
// strm 0: LDS-tiled transpose of rgb [c][hi*48+wi] -> Xt[n=wi*48+hi][c].
//   Reads 256B contiguous per c-row; writes 256B contiguous per token-row.
// strm 1: depth conv1x1+ReLU+bilinear computed per token, written 64B/lane.
__global__ __launch_bounds__(256) void xprep_kernel(
    const float* __restrict__ rgb, const float* __restrict__ dep,
    const float* __restrict__ w_exp, const float* __restrict__ b_exp,
    float* __restrict__ Xt)
{
    int t = blockIdx.x;            // 0..35 (64 spatial positions each)
    int z = blockIdx.y;            // b*2 + strm
    int b = z >> 1, strm = z & 1;
    __shared__ float Ls[64][65];   // [c][mi_local], pad 65 -> transpose-read 2-way max
    int tid = threadIdx.x;

    if (strm == 0) {
        const float* src = rgb + (size_t)b * C * NTOK + t * 64;
        #pragma unroll
        for (int p = 0; p < 4; ++p) {
            int idx = tid + p * 256;
            int c = idx >> 4, m4 = (idx & 15) * 4;
            *(float4*)&Ls[c][m4] = *(const float4*)&src[(size_t)c * NTOK + m4];
        }
        __syncthreads();
        #pragma unroll
        for (int p = 0; p < 4; ++p) {
            int idx = tid + p * 256;
            int row = idx >> 4, l = idx & 15;
            int mi = t * 64 + row;
            int hi = mi / 48, wi = mi % 48;    // rgb memory coords
            int n  = wi * 48 + hi;             // token index
            float4 v;
            v.x = Ls[4*l + 0][row];
            v.y = Ls[4*l + 1][row];
            v.z = Ls[4*l + 2][row];
            v.w = Ls[4*l + 3][row];
            *(float4*)&Xt[((size_t)z * NTOK + n) * 64 + 4*l] = v;
        }
    } else {
        int tok_l = tid >> 2, cq = (tid & 3) * 16;
        int n = t * 64 + tok_l;
        int wi = n / HH, hi = n % HH;
        float cy = 0.5f * hi - 0.25f, cx = 0.5f * wi - 0.25f;
        float fy0 = floorf(cy), fx0 = floorf(cx);
        float fy = cy - fy0, fx = cx - fx0;
        int y0 = max((int)fy0, 0), x0 = max((int)fx0, 0);
        int y1 = min((int)fy0 + 1, 23), x1 = min((int)fx0 + 1, 23);
        const float* dp = dep + b * 576;
        float d00 = dp[y0*24 + x0], d01 = dp[y0*24 + x1];
        float d10 = dp[y1*24 + x0], d11 = dp[y1*24 + x1];
        float* orow = &Xt[((size_t)z * NTOK + n) * 64];
        #pragma unroll
        for (int cc = 0; cc < 16; cc += 4) {
            float4 v;
            #pragma unroll
            for (int j = 0; j < 4; ++j) {
                int c = cq + cc + j;
                float w = w_exp[c], bb = b_exp[c];
                float r00 = fmaxf(w*d00 + bb, 0.f), r01 = fmaxf(w*d01 + bb, 0.f);
                float r10 = fmaxf(w*d10 + bb, 0.f), r11 = fmaxf(w*d11 + bb, 0.f);
                float val = (1.f-fy)*((1.f-fx)*r00 + fx*r01) + fy*((1.f-fx)*r10 + fx*r11);
                ((float*)&v)[j] = val;
            }
            *(float4*)&orow[cq + cc] = v;
        }
    }
}

// Fused Q,K,V GEMMs per (tile,b,strm). grid(72, 4), 256 thr, 32-token tiles.
// X read contiguously from Xt. Q,K -> [sb][h][n][8] bf16 (Q pre-scaled);
// V -> TRANSPOSED [sb][h][d][n].
__global__ __launch_bounds__(256) void qkv_kernel(
    const float* __restrict__ Xt,
    const float* __restrict__ w_rq, const float* __restrict__ w_rk, const float* __restrict__ w_rv,
    const float* __restrict__ w_dq, const float* __restrict__ w_dk, const float* __restrict__ w_dv,
    bf16_t* __restrict__ Qb, bf16_t* __restrict__ Kb, bf16_t* __restrict__ VT)
{
    int tile = blockIdx.x;           // 0..71 (32 tokens each)
    int z    = blockIdx.y;           // b*2 + strm
    int b = z >> 1, strm = z & 1;
    int sb = strm*2 + b;

    __shared__ float Xs[32][68];
    __shared__ float Ws[64][68];
    int tid = threadIdx.x;
    #pragma unroll
    for (int p = 0; p < 2; ++p) {
        int idx = tid + p*256;
        int r = idx >> 4, c4 = (idx & 15) * 4;
        *(float4*)&Xs[r][c4] = *(const float4*)&Xt[((size_t)z*NTOK + tile*32 + r)*64 + c4];
    }
    int sr = tid >> 4, sc = (tid & 15) * 4;
    int ty = tid >> 4, tx = tid & 15;

    #pragma unroll
    for (int m = 0; m < 3; ++m) {
        const float* W = strm ? (m == 0 ? w_dq : m == 1 ? w_dk : w_dv)
                              : (m == 0 ? w_rq : m == 1 ? w_rk : w_rv);
        __syncthreads();   // Xs ready (m=0) / prior GEMM done reading Ws (m>0)
        #pragma unroll
        for (int rr = 0; rr < 4; ++rr) {
            int r = rr*16 + sr;
            *(float4*)&Ws[r][sc] = *(const float4*)&W[r*64 + sc];
        }
        __syncthreads();

        float acc[2][4] = {};
        #pragma unroll
        for (int k = 0; k < 64; k += 4) {
            float4 xv[2], wv4[4];
            #pragma unroll
            for (int i = 0; i < 2; ++i) xv[i] = *(const float4*)&Xs[2*ty + i][k];
            #pragma unroll
            for (int j = 0; j < 4; ++j) wv4[j] = *(const float4*)&Ws[tx + 16*j][k];
            #pragma unroll
            for (int i = 0; i < 2; ++i)
                #pragma unroll
                for (int j = 0; j < 4; ++j)
                    acc[i][j] += xv[i].x*wv4[j].x + xv[i].y*wv4[j].y + xv[i].z*wv4[j].z + xv[i].w*wv4[j].w;
        }
        float scale = (m == 0) ? (0.35355339059327373f * 1.4426950408889634f) : 1.0f;
        #pragma unroll
        for (int j = 0; j < 4; ++j) {
            int o = tx + 16*j;
            int h = o >> 3, d = o & 7;
            #pragma unroll
            for (int i = 0; i < 2; ++i) {
                int n = tile*32 + 2*ty + i;
                bf16_t v = f2bf(acc[i][j] * scale);
                if (m == 0)      Qb[(((size_t)sb*8 + h)*NTOK + n)*8 + d] = v;
                else if (m == 1) Kb[(((size_t)sb*8 + h)*NTOK + n)*8 + d] = v;
                else             VT[(((size_t)sb*8 + h)*8 + d)*NTOK + n] = v;
            }
        }
    }
}

// MFMA flash attention. grid(36, 8, 4): qt-group x head x (b*2+which).
// 256 thr = 4 INDEPENDENT waves (no __syncthreads); wave w handles qtile
// blockIdx.x*4+w = 16 queries, looping 72 chunks of 32 keys:
//   S(16x32) = 2x mfma_16x16x32 (head dim in quad0, quads1-3 zero)
//   P = exp2(S) (no-max; proven) -> bf16 trunc -> per-wave LDS -> A-frag
//   O_aug(16x16) += P x V_aug  (V dims at n<8, ONES at n=8 -> l in col 8)
// Pls row stride 40 bf16 (80B): b128 read starts land on 8 distinct 4-bank
// groups, 2-way max (free).
__global__ __launch_bounds__(256) void attn_kernel(
    const bf16_t* __restrict__ Qb, const bf16_t* __restrict__ Kb,
    const bf16_t* __restrict__ VT,
    float* __restrict__ AOr, float* __restrict__ AOd)
{
    int h = blockIdx.y;
    int z = blockIdx.z;
    int b = z >> 1, which = z & 1;
    int qsb = which * 2 + b;
    int ksb = (1 - which) * 2 + b;
    const bf16_t* Q  = Qb + ((size_t)qsb * 8 + h) * NTOK * 8;
    const bf16_t* K  = Kb + ((size_t)ksb * 8 + h) * NTOK * 8;
    const bf16_t* Vt = VT + ((size_t)ksb * 8 + h) * 8 * NTOK;  // [d][key]
    float* AO = which ? AOd : AOr;

    __shared__ __align__(16) bf16_t Pls[4][16][40];  // padded rows (5 KB)
    __shared__ __align__(16) float  Ols[4][16][16];  // per-wave O tiles (4 KB)

    int tid = threadIdx.x;
    int t = tid & 63, w = tid >> 6;
    int m16 = t & 15, quad = t >> 4;
    int qt = blockIdx.x * 4 + w;       // 0..143
    int n0 = qt * 16;

    const bf16x8 zf = {0,0,0,0,0,0,0,0};
    const bf16x8 onesf = {0x3F80,0x3F80,0x3F80,0x3F80,0x3F80,0x3F80,0x3F80,0x3F80};
    const f32x4 cz = {0.f, 0.f, 0.f, 0.f};

    // Q fragment: A[m=lane&15][k=quad*8+j]; only quad 0 (dims 0-7) real.
    bf16x8 qf = (quad == 0) ? *(const bf16x8*)&Q[(size_t)(n0 + m16) * 8] : zf;

    f32x4 oacc = cz;

    #pragma unroll 1
    for (int ck = 0; ck < 72; ++ck) {
        int k0 = ck * 32;
        bf16x8 kf0 = (quad == 0) ? *(const bf16x8*)&K[(size_t)(k0 + m16) * 8]      : zf;
        bf16x8 kf1 = (quad == 0) ? *(const bf16x8*)&K[(size_t)(k0 + 16 + m16) * 8] : zf;
        bf16x8 vf = (m16 < 8) ? *(const bf16x8*)&Vt[(size_t)m16 * NTOK + k0 + quad * 8]
                  : (m16 == 8 ? onesf : zf);

        f32x4 s0 = __builtin_amdgcn_mfma_f32_16x16x32_bf16(qf, kf0, cz, 0, 0, 0);
        f32x4 s1 = __builtin_amdgcn_mfma_f32_16x16x32_bf16(qf, kf1, cz, 0, 0, 0);

        #pragma unroll
        for (int r = 0; r < 4; ++r) {
            float p0 = __builtin_amdgcn_exp2f(s0[r]);
            float p1 = __builtin_amdgcn_exp2f(s1[r]);
            Pls[w][quad*4 + r][m16]      = (bf16_t)(__float_as_uint(p0) >> 16);
            Pls[w][quad*4 + r][m16 + 16] = (bf16_t)(__float_as_uint(p1) >> 16);
        }
        bf16x8 pf = *(const bf16x8*)&Pls[w][m16][quad * 8];
        oacc = __builtin_amdgcn_mfma_f32_16x16x32_bf16(pf, vf, oacc, 0, 0, 0);
    }

    #pragma unroll
    for (int r = 0; r < 4; ++r)
        Ols[w][quad*4 + r][m16] = oacc[r];
    #pragma unroll
    for (int e = 0; e < 2; ++e) {
        int idx = t * 2 + e;           // 0..127 = 16 q x 8 d
        int qq = idx >> 3, d = idx & 7;
        float val = Ols[w][qq][d] / Ols[w][qq][8];
        AO[((size_t)b * NTOK + n0 + qq) * 64 + 8 * h + d] = val;
    }
}

// Fused 2x K=64 GEMM (W1,W2) + beff + GELU + LDS-restage + COALESCED store.
// grid(72, 2): 32-token tiles x batch. out is [B][C][N] linear in token n,
// so lanes along n give full 64B lines (fixes R15's 40 MB WRITE_SIZE).
__global__ __launch_bounds__(256) void outcomp_kernel(
    const float* __restrict__ AOr, const float* __restrict__ AOd,
    const float* __restrict__ W1, const float* __restrict__ W2,
    const float* __restrict__ beff, float* __restrict__ out)
{
    int tile = blockIdx.x;       // 0..71
    int b    = blockIdx.y;
    int n0 = tile * 32;
    __shared__ float Ar[32][68];
    __shared__ float Ad[32][68];
    __shared__ float W1s[64][68];
    __shared__ float W2s[64][68];
    int tid = threadIdx.x;
    #pragma unroll
    for (int pass = 0; pass < 2; ++pass) {
        int idx = tid + pass*256;
        int row = idx >> 4, c4 = (idx & 15) * 4;
        *(float4*)&Ar[row][c4] = *(const float4*)&AOr[((size_t)b*NTOK + n0 + row)*64 + c4];
        *(float4*)&Ad[row][c4] = *(const float4*)&AOd[((size_t)b*NTOK + n0 + row)*64 + c4];
    }
    {
        int sr = tid >> 4, sc4 = (tid & 15) * 4;
        #pragma unroll
        for (int rr = 0; rr < 4; ++rr) {
            int r = rr*16 + sr;
            *(float4*)&W1s[r][sc4] = *(const float4*)&W1[r*64 + sc4];
            *(float4*)&W2s[r][sc4] = *(const float4*)&W2[r*64 + sc4];
        }
    }
    __syncthreads();

    int tx = tid & 15, ty = tid >> 4;
    float g[2][4] = {};
    #pragma unroll
    for (int k = 0; k < 64; k += 4) {
        float4 xr0 = *(const float4*)&Ar[2*ty][k];
        float4 xr1 = *(const float4*)&Ar[2*ty + 1][k];
        float4 xd0 = *(const float4*)&Ad[2*ty][k];
        float4 xd1 = *(const float4*)&Ad[2*ty + 1][k];
        #pragma unroll
        for (int jj = 0; jj < 4; ++jj) {
            float4 w1 = *(const float4*)&W1s[tx + 16*jj][k];
            float4 w2 = *(const float4*)&W2s[tx + 16*jj][k];
            g[0][jj] += xr0.x*w1.x + xr0.y*w1.y + xr0.z*w1.z + xr0.w*w1.w
                      + xd0.x*w2.x + xd0.y*w2.y + xd0.z*w2.z + xd0.w*w2.w;
            g[1][jj] += xr1.x*w1.x + xr1.y*w1.y + xr1.z*w1.z + xr1.w*w1.w
                      + xd1.x*w2.x + xd1.y*w2.y + xd1.z*w2.z + xd1.w*w2.w;
        }
    }

    // Restage GELU results into LDS (reuse W1s storage, stride 40 so 8-lane
    // float4 read groups hit all 8 4-bank groups), then coalesced store.
    __syncthreads();                   // everyone done reading W1s/W2s
    float* Gs = &W1s[0][0];            // viewed as [64 o][stride 40]
    #pragma unroll
    for (int jj = 0; jj < 4; ++jj) {
        int o = tx + 16*jj;
        float be = beff[o];
        #pragma unroll
        for (int i = 0; i < 2; ++i) {
            float x = g[i][jj] + be;
            float gl = 0.5f * x * (1.0f + erff(x * 0.70710678118654752f));
            Gs[o*40 + 2*ty + i] = gl;
        }
    }
    __syncthreads();
    #pragma unroll
    for (int p = 0; p < 2; ++p) {
        int idx = tid + p*256;         // 512 = 64 o x 8 float4-segments
        int o = idx >> 3, s = idx & 7;
        float4 v = *(const float4*)&Gs[o*40 + 4*s];
        *(float4*)&out[((size_t)(b*C + o))*NTOK + n0 + 4*s] = v;
    }
}

// ===========================================================================
// FALLBACK (R9 big path, proven): ws >= 3,538,944 B.
// ===========================================================================
__global__ __launch_bounds__(256) void kv_all_kernel(
    const float* __restrict__ rgb, const float* __restrict__ dep,
    const float* __restrict__ w_exp, const float* __restrict__ b_exp,
    const float* __restrict__ w_rk, const float* __restrict__ w_rv,
    const float* __restrict__ w_dk, const float* __restrict__ w_dv,
    bf16_t* __restrict__ Kr, bf16_t* __restrict__ Vr,
    bf16_t* __restrict__ Kd, bf16_t* __restrict__ Vd)
{
    int tile = blockIdx.x;
    int m    = blockIdx.y;
    int z    = blockIdx.z;
    int b = z >> 1, strm = z & 1;
    const float* W = strm ? (m ? w_dv : w_dk) : (m ? w_rv : w_rk);
    bf16_t* O = (strm ? (m ? Vd : Kd) : (m ? Vr : Kr))
              + ((size_t)b * NTOK + tile * 64) * 64;

    __shared__ float Xs[64][68];
    __shared__ float Ws[64][68];
    int tid = threadIdx.x;
    {
        int r = tid & 63, c0 = tid >> 6;
        stage_x_row(&Xs[r][0], rgb, dep, w_exp, b_exp, b, tile*64 + r, strm, c0, 4);
    }
    int sr = tid >> 4, sc = (tid & 15) * 4;
    #pragma unroll
    for (int rr = 0; rr < 4; ++rr) {
        int r = rr*16 + sr;
        *(float4*)&Ws[r][sc] = *(const float4*)&W[r*64 + sc];
    }
    __syncthreads();

    int ty = tid >> 4, tx = tid & 15;
    float acc[4][4] = {};
    #pragma unroll
    for (int k = 0; k < 64; k += 4) {
        float4 xv[4], wv4[4];
        #pragma unroll
        for (int i = 0; i < 4; ++i) xv[i] = *(const float4*)&Xs[4*ty + i][k];
        #pragma unroll
        for (int j = 0; j < 4; ++j) wv4[j] = *(const float4*)&Ws[tx + 16*j][k];
        #pragma unroll
        for (int i = 0; i < 4; ++i)
            #pragma unroll
            for (int j = 0; j < 4; ++j)
                acc[i][j] += xv[i].x*wv4[j].x + xv[i].y*wv4[j].y + xv[i].z*wv4[j].z + xv[i].w*wv4[j].w;
    }
    #pragma unroll
    for (int i = 0; i < 4; ++i)
        #pragma unroll
        for (int j = 0; j < 4; ++j)
            O[(4*ty + i)*64 + tx + 16*j] = f2bf(acc[i][j]);
}

__global__ __launch_bounds__(256) void attn_all_kernel(
    const float* __restrict__ rgb, const float* __restrict__ dep,
    const float* __restrict__ w_exp, const float* __restrict__ b_exp,
    const float* __restrict__ w_rq, const float* __restrict__ w_dq,
    const bf16_t* __restrict__ Kr, const bf16_t* __restrict__ Vr,
    const bf16_t* __restrict__ Kd, const bf16_t* __restrict__ Vd,
    bf16_t* __restrict__ AOr, bf16_t* __restrict__ AOd)
{
    int qt = blockIdx.x;
    int h  = blockIdx.y;
    int z  = blockIdx.z;
    int b = z >> 1, which = z & 1;
    const float* wq = which ? w_dq : w_rq;
    const bf16_t* K = which ? Kr : Kd;
    const bf16_t* V = which ? Vr : Vd;
    bf16_t* AO      = which ? AOd : AOr;

    __shared__ float Xs[64][68];
    __shared__ float Wqs[8][64];
    __shared__ __align__(16) float Ks[4][64][KVSTRIDE];
    __shared__ __align__(16) float Vs[4][64][KVSTRIDE];

    int tid = threadIdx.x;
    int t = tid & 63;
    int w = tid >> 6;
    int n = qt * 64 + t;

    stage_x_row(&Xs[t][0], rgb, dep, w_exp, b_exp, b, n, which == 0 ? 0 : 1, w, 4);
    if (w == 0) {
        #pragma unroll
        for (int d = 0; d < 8; ++d) Wqs[d][t] = wq[(8*h + d)*64 + t];
    }
    __syncthreads();

    const float sc = 0.35355339059327373f * 1.4426950408889634f;
    float q[8];
    #pragma unroll
    for (int d = 0; d < 8; ++d) {
        float s = 0.f;
        #pragma unroll 8
        for (int c = 0; c < 64; ++c) s += Xs[t][c] * Wqs[d][c];
        q[d] = s * sc;
    }

    float mrun = -INFINITY, l = 0.f;
    float acc[8] = {};

    #pragma unroll 1
    for (int st = 0; st < 9; ++st) {
        __syncthreads();
        {
            size_t g = ((size_t)b * NTOK + (w*576 + st*64 + t)) * 64 + 8 * h;
            *(float4*)&Ks[w][t][0] = ld_bf4(&K[g]);
            *(float4*)&Ks[w][t][4] = ld_bf4(&K[g + 4]);
            *(float4*)&Vs[w][t][0] = ld_bf4(&V[g]);
            *(float4*)&Vs[w][t][4] = ld_bf4(&V[g + 4]);
        }
        __syncthreads();

        for (int g8 = 0; g8 < 8; ++g8) {
            float s[8];
            #pragma unroll
            for (int u = 0; u < 8; ++u) {
                const float4 ka = *(const float4*)&Ks[w][g8*8 + u][0];
                const float4 kb = *(const float4*)&Ks[w][g8*8 + u][4];
                s[u] = q[0]*ka.x + q[1]*ka.y + q[2]*ka.z + q[3]*ka.w
                     + q[4]*kb.x + q[5]*kb.y + q[6]*kb.z + q[7]*kb.w;
            }
            float tm = fmaxf(fmaxf(fmaxf(s[0],s[1]), fmaxf(s[2],s[3])),
                             fmaxf(fmaxf(s[4],s[5]), fmaxf(s[6],s[7])));
            float mn = fmaxf(mrun, tm);
            float alpha = __builtin_amdgcn_exp2f(mrun - mn);
            float ps = 0.f;
            #pragma unroll
            for (int u = 0; u < 8; ++u) { s[u] = __builtin_amdgcn_exp2f(s[u] - mn); ps += s[u]; }
            l = l * alpha + ps;
            #pragma unroll
            for (int d = 0; d < 8; ++d) acc[d] *= alpha;
            #pragma unroll
            for (int u = 0; u < 8; ++u) {
                const float4 va = *(const float4*)&Vs[w][g8*8 + u][0];
                const float4 vb = *(const float4*)&Vs[w][g8*8 + u][4];
                acc[0] += s[u]*va.x; acc[1] += s[u]*va.y; acc[2] += s[u]*va.z; acc[3] += s[u]*va.w;
                acc[4] += s[u]*vb.x; acc[5] += s[u]*vb.y; acc[6] += s[u]*vb.z; acc[7] += s[u]*vb.w;
            }
            mrun = mn;
        }
    }

    float* part = &Xs[0][0];
    __syncthreads();
    {
        float* p = &part[(w*64 + t) * 10];
        p[0] = mrun; p[1] = l;
        #pragma unroll
        for (int d = 0; d < 8; ++d) p[2 + d] = acc[d];
    }
    __syncthreads();
    if (tid < 64) {
        float M = -INFINITY;
        #pragma unroll
        for (int v = 0; v < 4; ++v) M = fmaxf(M, part[(v*64 + t)*10]);
        float L = 0.f, o[8] = {};
        #pragma unroll
        for (int v = 0; v < 4; ++v) {
            const float* p = &part[(v*64 + t)*10];
            float al = __builtin_amdgcn_exp2f(p[0] - M);
            L += p[1] * al;
            #pragma unroll
            for (int d = 0; d < 8; ++d) o[d] += p[2 + d] * al;
        }
        float inv = 1.0f / L;
        uint4 ov;
        ov.x = pack2(o[0]*inv, o[1]*inv);
        ov.y = pack2(o[2]*inv, o[3]*inv);
        ov.z = pack2(o[4]*inv, o[5]*inv);
        ov.w = pack2(o[6]*inv, o[7]*inv);
        *(uint4*)&AO[((size_t)b * NTOK + n) * 64 + 8 * h] = ov;
    }
}

__global__ __launch_bounds__(256) void projcomp_all_kernel(
    const bf16_t* __restrict__ AOr, const bf16_t* __restrict__ AOd,
    const float* __restrict__ w_rp, const float* __restrict__ b_rp,
    const float* __restrict__ w_dp, const float* __restrict__ b_dp,
    const float* __restrict__ w_comp, const float* __restrict__ b_comp,
    float* __restrict__ out)
{
    int tile = blockIdx.x;
    int b    = blockIdx.y;
    __shared__ float A[64][68];
    __shared__ float Bf[64][68];
    __shared__ float Pf[64][68];
    int tid = threadIdx.x;
    int sr = tid >> 4, sc = (tid & 15) * 4;
    int ty = tid >> 4, tx = tid & 15;
    float G[4][4] = {};

    #pragma unroll
    for (int half = 0; half < 2; ++half) {
        const bf16_t* AOx = half ? AOd : AOr;
        const float* Wp   = half ? w_dp : w_rp;
        const float* bp   = half ? b_dp : b_rp;
        #pragma unroll
        for (int rr = 0; rr < 4; ++rr) {
            int r = rr*16 + sr;
            *(float4*)&A[r][sc]  = ld_bf4(&AOx[((size_t)b*NTOK + tile*64 + r)*64 + sc]);
            *(float4*)&Bf[r][sc] = *(const float4*)&Wp[r*64 + sc];
        }
        __syncthreads();
        float acc[4][4] = {};
        #pragma unroll
        for (int k = 0; k < 64; k += 4) {
            float4 xv[4], wv[4];
            #pragma unroll
            for (int i = 0; i < 4; ++i) xv[i] = *(const float4*)&A[4*ty + i][k];
            #pragma unroll
            for (int j = 0; j < 4; ++j) wv[j] = *(const float4*)&Bf[tx + 16*j][k];
            #pragma unroll
            for (int i = 0; i < 4; ++i)
                #pragma unroll
                for (int j = 0; j < 4; ++j)
                    acc[i][j] += xv[i].x*wv[j].x + xv[i].y*wv[j].y + xv[i].z*wv[j].z + xv[i].w*wv[j].w;
        }
        __syncthreads();
        #pragma unroll
        for (int j = 0; j < 4; ++j) {
            float bj = bp[tx + 16*j];
            #pragma unroll
            for (int i = 0; i < 4; ++i)
                Pf[4*ty + i][tx + 16*j] = acc[i][j] + bj;
        }
        #pragma unroll
        for (int rr = 0; rr < 4; ++rr) {
            int r = rr*16 + sr;
            *(float4*)&Bf[r][sc] = *(const float4*)&w_comp[r*128 + half*64 + sc];
        }
        __syncthreads();
        #pragma unroll
        for (int k = 0; k < 64; k += 4) {
            float4 xv[4], wv[4];
            #pragma unroll
            for (int i = 0; i < 4; ++i) xv[i] = *(const float4*)&Pf[4*ty + i][k];
            #pragma unroll
            for (int j = 0; j < 4; ++j) wv[j] = *(const float4*)&Bf[tx + 16*j][k];
            #pragma unroll
            for (int i = 0; i < 4; ++i)
                #pragma unroll
                for (int j = 0; j < 4; ++j)
                    G[i][j] += xv[i].x*wv[j].x + xv[i].y*wv[j].y + xv[i].z*wv[j].z + xv[i].w*wv[j].w;
        }
        __syncthreads();
    }

    #pragma unroll
    for (int j = 0; j < 4; ++j) {
        int o = tx + 16*j;
        float bj = b_comp[o];
        #pragma unroll
        for (int i = 0; i < 4; ++i) {
            int n = tile*64 + 4*ty + i;
            int wi = n / HH, hi = n % HH;
            float x = G[i][j] + bj;
            float g = 0.5f * x * (1.0f + erff(x * 0.70710678118654752f));
            out[((b*C + o)*WW + wi)*HH + hi] = g;
        }
    }
}

// ---------------------------------------------------------------------------
extern "C" void kernel_launch(void* const* d_in, const int* in_sizes, int n_in,
                              void* d_out, int out_size, void* d_ws, size_t ws_size,
                              hipStream_t stream) {
    const float* rgb_fea = (const float*)d_in[0];
    const float* depth   = (const float*)d_in[1];
    const float* w_exp   = (const float*)d_in[2];
    const float* b_exp   = (const float*)d_in[3];
    const float* w_rq    = (const float*)d_in[4];
    const float* w_rk    = (const float*)d_in[5];
    const float* w_rv    = (const float*)d_in[6];
    const float* w_dq    = (const float*)d_in[7];
    const float* w_dk    = (const float*)d_in[8];
    const float* w_dv    = (const float*)d_in[9];
    const float* w_rp    = (const float*)d_in[10];
    const float* b_rp    = (const float*)d_in[11];
    const float* w_dp    = (const float*)d_in[12];
    const float* b_dp    = (const float*)d_in[13];
    const float* w_comp  = (const float*)d_in[14];
    const float* b_comp  = (const float*)d_in[15];
    float* out = (float*)d_out;

    if (ws_size >= 5931264) {
        char* Wb = (char*)d_ws;
        bf16_t* Qb  = (bf16_t*)Wb;                 // [4][8][2304][8] bf16
        bf16_t* Kb  = (bf16_t*)(Wb + 1179648);     // [4][8][2304][8] bf16
        bf16_t* VT  = (bf16_t*)(Wb + 2359296);     // [4][8][8][2304] bf16
        float* AOr  = (float*)(Wb + 3538944);      // [2][2304][64] fp32
        float* AOd  = (float*)(Wb + 4718592);
        float* W1   = (float*)(Wb + 5898240);
        float* W2   = (float*)(Wb + 5914624);
        float* beff = (float*)(Wb + 5931008);
        // Xt aliases AOr+AOd (2,359,296 B): dead once qkv completes, and
        // attn (the first AO writer) is stream-ordered after qkv.
        float* Xt   = (float*)(Wb + 3538944);      // [4][2304][64] fp32

        wprep_kernel<<<dim3(4, 2), dim3(256), 0, stream>>>(
            w_rp, w_dp, w_comp, b_rp, b_dp, b_comp, W1, W2, beff);
        xprep_kernel<<<dim3(36, 4), dim3(256), 0, stream>>>(
            rgb_fea, depth, w_exp, b_exp, Xt);
        qkv_kernel<<<dim3(72, 4), dim3(256), 0, stream>>>(
            Xt, w_rq, w_rk, w_rv, w_dq, w_dk, w_dv, Qb, Kb, VT);
        attn_kernel<<<dim3(36, 8, 4), dim3(256), 0, stream>>>(
            Qb, Kb, VT, AOr, AOd);
        outcomp_kernel<<<dim3(72, 2), dim3(256), 0, stream>>>(
            AOr, AOd, W1, W2, beff, out);
    } else {
        // R9 big path (proven)
        const size_t BUF = (size_t)BATCH * NTOK * 64;
        bf16_t* Kr  = (bf16_t*)d_ws;
        bf16_t* Vr  = Kr + BUF;
        bf16_t* Kd  = Vr + BUF;
        bf16_t* Vd  = Kd + BUF;
        bf16_t* AOr = Vd + BUF;
        bf16_t* AOd = AOr + BUF;
        kv_all_kernel<<<dim3(36, 2, 4), dim3(256), 0, stream>>>(
            rgb_fea, depth, w_exp, b_exp, w_rk, w_rv, w_dk, w_dv, Kr, Vr, Kd, Vd);
        attn_all_kernel<<<dim3(36, 8, 4), dim3(256), 0, stream>>>(
            rgb_fea, depth, w_exp, b_exp, w_rq, w_dq, Kr, Vr, Kd, Vd, AOr, AOd);
        projcomp_all_kernel<<<dim3(36, 2), dim3(256), 0, stream>>>(
            AOr, AOd, w_rp, b_rp, w_dp, b_dp, w_comp, b_comp, out);
    }
}